// Round 4
// baseline (1529.894 us; speedup 1.0000x reference)
//
#include <hip/hip_runtime.h>
#include <math.h>

// =====================================================================
// ViT discriminator forward — round 4.
//  * attn: barrier-free streaming — K/V MFMA fragments loaded straight
//    from global (L2-resident), LDS only for wave-private P transpose.
//    defer-max (THR=8) kills per-chunk softmax reductions; row-sum l
//    comes free from a ones-row appended to Vt (accO[6]).
//  * mgemm: global_load_lds width-16 staging, linear [128][32] LDS,
//    one barrier per K-step (2-phase template).
// =====================================================================

#define BATCH   16
#define TSEQ    1025
#define DMODEL  384
#define NHEAD   4
#define HDIM    96
#define NBLK    3
#define FFDIM   1536
#define IMGSZ   512
#define NPATCHI 1024
#define MROWS   (BATCH*TSEQ)      // 16400
#define MPATCH  (BATCH*NPATCHI)   // 16384
#define KPE     768
#define VTS     1088              // padded t-stride of Vt (17*64)
#define VROWS   112               // 96 d-rows + ones row (96) + 15 zero rows
#define ATT_SCALE 0.10206207261596577f  // 1/sqrt(96)

typedef __attribute__((ext_vector_type(8))) __bf16 bf16x8;
typedef __attribute__((ext_vector_type(4))) float  f32x4;
typedef unsigned int u32;

__device__ __forceinline__ f32x4 fzero4() {
  f32x4 v; v[0] = 0.f; v[1] = 0.f; v[2] = 0.f; v[3] = 0.f; return v;
}

// async global->LDS, 16B per lane, LDS dest = wave-uniform base + lane*16
__device__ __forceinline__ void gl_lds16(const __bf16* g, __bf16* l) {
  __builtin_amdgcn_global_load_lds(
      (const __attribute__((address_space(1))) u32*)g,
      (__attribute__((address_space(3))) u32*)l, 16, 0, 0);
}

// ---------------------------------------------------------------------
// bf16 MFMA GEMM: C[M,N] = A[M,K] @ Bt[N,K]^T, K%32==0, N%128==0.
// global_load_lds staging, linear LDS, 1 barrier / K-step.
// NOTE: edge blocks read A rows >= M (lands in allocated ws; never stored).
// EPI bits: 1=+bias, 2=relu, 4=+res(fp32), 8=write Cf(fp32), 16=write Cb(bf16)
// ---------------------------------------------------------------------
template<int EPI>
__global__ __launch_bounds__(256, 4) void mgemm_k(
    const __bf16* __restrict__ A, const __bf16* __restrict__ Bt,
    const float* __restrict__ bias, const float* __restrict__ res,
    float* __restrict__ Cf, __bf16* __restrict__ Cb, int M, int N, int K)
{
  __shared__ __bf16 Al[2][128][32];
  __shared__ __bf16 Bl[2][128][32];
  const int tid = threadIdx.x;
  const int lane = tid & 63;
  const int w = tid >> 6;
  const int wr = w >> 1, wc = w & 1;
  const int l15 = lane & 15, g = lane >> 4;
  const int row0 = blockIdx.x * 128, col0 = blockIdx.y * 128;
  // staging geometry: wave w, inst j covers rows w*32+j*16 .. +15;
  // lane l -> row +(l>>2), col elems (l&3)*8 (16B) — linear in LDS.
  const int sr = w * 32 + (lane >> 2);
  const int sc = (lane & 3) * 8;
  const __bf16* Ab = A  + (size_t)(row0 + sr) * K + sc;
  const __bf16* Bb = Bt + (size_t)(col0 + sr) * K + sc;

  f32x4 acc[4][4];
#pragma unroll
  for (int i = 0; i < 4; ++i)
#pragma unroll
    for (int j = 0; j < 4; ++j) acc[i][j] = fzero4();

  const int nk = K >> 5;
  auto stage = [&](int buf, int kt) {
#pragma unroll
    for (int j = 0; j < 2; ++j) {
      gl_lds16(Ab + (size_t)(j * 16) * K + kt * 32, &Al[buf][w * 32 + j * 16][0]);
      gl_lds16(Bb + (size_t)(j * 16) * K + kt * 32, &Bl[buf][w * 32 + j * 16][0]);
    }
  };

  stage(0, 0);
  __syncthreads();
  int cur = 0;
  for (int kt = 0; kt < nk; ++kt) {
    if (kt + 1 < nk) stage(cur ^ 1, kt + 1);
    bf16x8 af[4], bfr[4];
#pragma unroll
    for (int mi = 0; mi < 4; ++mi)
      af[mi] = *(const bf16x8*)&Al[cur][wr * 64 + mi * 16 + l15][g * 8];
#pragma unroll
    for (int ni = 0; ni < 4; ++ni)
      bfr[ni] = *(const bf16x8*)&Bl[cur][wc * 64 + ni * 16 + l15][g * 8];
    __builtin_amdgcn_s_setprio(1);
#pragma unroll
    for (int mi = 0; mi < 4; ++mi)
#pragma unroll
      for (int ni = 0; ni < 4; ++ni)
        acc[mi][ni] = __builtin_amdgcn_mfma_f32_16x16x32_bf16(
            af[mi], bfr[ni], acc[mi][ni], 0, 0, 0);
    __builtin_amdgcn_s_setprio(0);
    __syncthreads();
    cur ^= 1;
  }
#pragma unroll
  for (int ni = 0; ni < 4; ++ni) {
    const int gc = col0 + wc * 64 + ni * 16 + l15;
    const float bv = (EPI & 1) ? bias[gc] : 0.f;
#pragma unroll
    for (int mi = 0; mi < 4; ++mi) {
#pragma unroll
      for (int r = 0; r < 4; ++r) {
        const int gr = row0 + wr * 64 + mi * 16 + g * 4 + r;
        if (gr >= M) continue;
        float v = acc[mi][ni][r] + bv;
        if (EPI & 2) v = fmaxf(v, 0.f);
        if (EPI & 4) v += res[(size_t)gr * N + gc];
        if (EPI & 8)  Cf[(size_t)gr * N + gc] = v;
        if (EPI & 16) Cb[(size_t)gr * N + gc] = (__bf16)v;
      }
    }
  }
}

// ---------------------------------------------------------------------
// V transpose: Vt[bh][VROWS][VTS]; rows 0..95 = V^T (zero-padded t>=TSEQ),
// row 96 = ones (row-sum trick), rows 97..111 = zeros.
// ---------------------------------------------------------------------
__global__ void vtr_k(const __bf16* __restrict__ qkv, __bf16* __restrict__ Vt)
{
  __shared__ __bf16 t[32][33];
  const int bh = blockIdx.z;
  const int bb = bh >> 2, hh = bh & 3;
  const int t0 = blockIdx.x * 32;
  const int d0 = blockIdx.y * 32;
  const int tx = threadIdx.x, ty = threadIdx.y;  // 32 x 8
  if (d0 >= 96) {   // constant rows 96..127 (only 96..111 exist)
#pragma unroll
    for (int i = 0; i < 4; ++i) {
      const int d = d0 + ty + 8 * i;
      if (d < VROWS)
        Vt[((size_t)bh * VROWS + d) * VTS + t0 + tx] =
            (d == 96) ? (__bf16)1.f : (__bf16)0.f;
    }
    return;
  }
#pragma unroll
  for (int i = 0; i < 4; ++i) {
    const int tt = t0 + ty + 8 * i;
    t[ty + 8 * i][tx] = (tt < TSEQ)
        ? qkv[(size_t)(bb * TSEQ + tt) * 1152 + 768 + hh * 96 + d0 + tx]
        : (__bf16)0.f;
  }
  __syncthreads();
#pragma unroll
  for (int i = 0; i < 4; ++i)
    Vt[((size_t)bh * VROWS + d0 + ty + 8 * i) * VTS + t0 + tx] = t[tx][ty + 8 * i];
}

// ---------------------------------------------------------------------
// Streaming MFMA distance attention (round 4): no block barriers.
// grid (17, 64), 4 waves; wave w owns q rows [qt*64+w*16, +16).
// K/V fragments loaded straight from global; LDS only for P transpose.
// accO[6] accumulates row-sum l via Vt's ones-row.
// ---------------------------------------------------------------------
__global__ __launch_bounds__(256, 3) void attn_k(
    const __bf16* __restrict__ qkv, const __bf16* __restrict__ Vtg,
    const float* __restrict__ sq2, const float* __restrict__ sk2,
    __bf16* __restrict__ O)
{
  __shared__ __bf16 Pl[64][72];   // wave-private 16-row slabs
  const int qt = blockIdx.x, bh = blockIdx.y;
  const int bb = bh >> 2, hh = bh & 3;
  const int tid = threadIdx.x;
  const int w = tid >> 6, lane = tid & 63;
  const int l15 = lane & 15, g = lane >> 4;
  const int q0 = qt * 64 + w * 16;
  const float* sq2h = sq2 + (size_t)bh * TSEQ;
  const float* sk2h = sk2 + (size_t)bh * TSEQ;
  const __bf16* kbp = qkv + (size_t)bb * TSEQ * 1152 + 384 + hh * 96;
  const __bf16* vbp = Vtg + (size_t)bh * VROWS * VTS;

  // Q fragments + per-row |q|^2
  bf16x8 qf[3];
  float sqv[4];
  {
    int qr = q0 + l15; if (qr > TSEQ - 1) qr = TSEQ - 1;
    const __bf16* qp = qkv + (size_t)(bb * TSEQ + qr) * 1152 + hh * 96 + g * 8;
#pragma unroll
    for (int kf = 0; kf < 3; ++kf) qf[kf] = *(const bf16x8*)(qp + kf * 32);
#pragma unroll
    for (int r = 0; r < 4; ++r) {
      int qq = q0 + g * 4 + r; if (qq > TSEQ - 1) qq = TSEQ - 1;
      sqv[r] = sq2h[qq];
    }
  }

  float mrun[4];
  f32x4 accO[7];                    // [6] = running row-sum l
#pragma unroll
  for (int r = 0; r < 4; ++r) mrun[r] = -INFINITY;
#pragma unroll
  for (int n = 0; n < 7; ++n) accO[n] = fzero4();

  for (int c = 0; c < 17; ++c) {
    const int kbase = c * 64;

    // ---- S = Q K^T, K-frags streamed from global ----
    f32x4 sf[4];
#pragma unroll
    for (int ks = 0; ks < 4; ++ks) sf[ks] = fzero4();
    {
      bf16x8 kb[4][3];
#pragma unroll
      for (int ks = 0; ks < 4; ++ks) {
        int krow = kbase + ks * 16 + l15; if (krow > TSEQ - 1) krow = TSEQ - 1;
        const __bf16* kp = kbp + (size_t)krow * 1152 + g * 8;
#pragma unroll
        for (int kf = 0; kf < 3; ++kf) kb[ks][kf] = *(const bf16x8*)(kp + kf * 32);
      }
      __builtin_amdgcn_s_setprio(1);
#pragma unroll
      for (int ks = 0; ks < 4; ++ks)
#pragma unroll
        for (int kf = 0; kf < 3; ++kf)
          sf[ks] = __builtin_amdgcn_mfma_f32_16x16x32_bf16(
              qf[kf], kb[ks][kf], sf[ks], 0, 0, 0);
      __builtin_amdgcn_s_setprio(0);
    }

    // ---- issue V-frag loads for ks2=0 (latency hides under softmax) ----
    bf16x8 vb0[7];
#pragma unroll
    for (int n = 0; n < 7; ++n)
      vb0[n] = *(const bf16x8*)(vbp + (size_t)(n * 16 + l15) * VTS + kbase + g * 8);

    // ---- distance scores ----
    float cm[4] = {-INFINITY, -INFINITY, -INFINITY, -INFINITY};
#pragma unroll
    for (int ks = 0; ks < 4; ++ks) {
      const int kgl = kbase + ks * 16 + l15;
      const bool kvld = (kgl < TSEQ);
      const float kv2 = sk2h[kvld ? kgl : 0];
#pragma unroll
      for (int r = 0; r < 4; ++r) {
        const float d2 = sqv[r] + kv2 - 2.f * sf[ks][r];
        const float s = kvld ? sqrtf(fmaxf(d2, 0.f)) * ATT_SCALE : -INFINITY;
        sf[ks][r] = s;
        cm[r] = fmaxf(cm[r], s);
      }
    }

    // ---- defer-max: rescale only when the chunk max grows past THR ----
    const bool okl = (cm[0] <= mrun[0] + 8.f) && (cm[1] <= mrun[1] + 8.f) &&
                     (cm[2] <= mrun[2] + 8.f) && (cm[3] <= mrun[3] + 8.f);
    if (!__all(okl)) {
#pragma unroll
      for (int r = 0; r < 4; ++r) {
        float v = cm[r];
        v = fmaxf(v, __shfl_xor(v, 1, 64));
        v = fmaxf(v, __shfl_xor(v, 2, 64));
        v = fmaxf(v, __shfl_xor(v, 4, 64));
        v = fmaxf(v, __shfl_xor(v, 8, 64));
        const float mn = fmaxf(mrun[r], v);
        const float f = __expf(mrun[r] - mn);
        mrun[r] = mn;
#pragma unroll
        for (int n = 0; n < 7; ++n) accO[n][r] *= f;
      }
    }

    // ---- P = exp(s - m), store to wave-private LDS slab ----
#pragma unroll
    for (int ks = 0; ks < 4; ++ks)
#pragma unroll
      for (int r = 0; r < 4; ++r)
        Pl[w * 16 + g * 4 + r][ks * 16 + l15] = (__bf16)__expf(sf[ks][r] - mrun[r]);

    // ---- O += P V (l accumulates in accO[6] via ones-row) ----
    bf16x8 vb1[7];
#pragma unroll
    for (int n = 0; n < 7; ++n)
      vb1[n] = *(const bf16x8*)(vbp + (size_t)(n * 16 + l15) * VTS + kbase + 32 + g * 8);
    bf16x8 pa0 = *(const bf16x8*)&Pl[w * 16 + l15][g * 8];
    bf16x8 pa1 = *(const bf16x8*)&Pl[w * 16 + l15][32 + g * 8];
    __builtin_amdgcn_s_setprio(1);
#pragma unroll
    for (int n = 0; n < 7; ++n)
      accO[n] = __builtin_amdgcn_mfma_f32_16x16x32_bf16(pa0, vb0[n], accO[n], 0, 0, 0);
#pragma unroll
    for (int n = 0; n < 7; ++n)
      accO[n] = __builtin_amdgcn_mfma_f32_16x16x32_bf16(pa1, vb1[n], accO[n], 0, 0, 0);
    __builtin_amdgcn_s_setprio(0);
  }

  // ---- normalize + store: l lives in accO[6][r] of lanes l15==0 ----
#pragma unroll
  for (int r = 0; r < 4; ++r) {
    const int qr = q0 + g * 4 + r;
    if (qr >= TSEQ) continue;
    const float lr = __shfl(accO[6][r], lane & 48, 64);
    const float inv = 1.f / lr;
#pragma unroll
    for (int n = 0; n < 6; ++n)
      O[(size_t)(bb * TSEQ + qr) * 384 + hh * 96 + n * 16 + l15] =
          (__bf16)(accO[n][r] * inv);
  }
}

// ---------------------------------------------------------------------
// im2col + fp32->bf16: Ai[16384][768]
// ---------------------------------------------------------------------
__global__ __launch_bounds__(256) void im2col_k(
    const float* __restrict__ x, __bf16* __restrict__ Ai)
{
  const int i = blockIdx.x * 256 + threadIdx.x;
  const int row = i / 96;
  const int k = (i - row * 96) * 8;
  const int b = row >> 10;
  const int pidx = row & 1023;
  const int py = pidx >> 5, px = pidx & 31;
  const int cc = k >> 8;
  const int rem = k & 255;
  const int p = rem >> 4, q = rem & 15;
  const float* src = x + ((size_t)((b * 3 + cc) * IMGSZ + py * 16 + p)) * IMGSZ
                       + px * 16 + q;
  const float4 a = *(const float4*)src;
  const float4 c4 = *(const float4*)(src + 4);
  bf16x8 o;
  o[0] = (__bf16)a.x;  o[1] = (__bf16)a.y;  o[2] = (__bf16)a.z;  o[3] = (__bf16)a.w;
  o[4] = (__bf16)c4.x; o[5] = (__bf16)c4.y; o[6] = (__bf16)c4.z; o[7] = (__bf16)c4.w;
  *(bf16x8*)&Ai[(size_t)i * 8] = o;
}

// ---------------------------------------------------------------------
__global__ void wt_k(const float* __restrict__ src, size_t srcZ,
                     __bf16* __restrict__ dst, size_t dstZ, int K, int N)
{
  __shared__ float t[32][33];
  const float* s = src + blockIdx.z * srcZ;
  __bf16* d = dst + blockIdx.z * dstZ;
  const int k0 = blockIdx.x * 32, n0 = blockIdx.y * 32;
  const int tx = threadIdx.x, ty = threadIdx.y;
#pragma unroll
  for (int i = 0; i < 4; ++i)
    t[ty + 8 * i][tx] = s[(size_t)(k0 + ty + 8 * i) * N + n0 + tx];
  __syncthreads();
#pragma unroll
  for (int i = 0; i < 4; ++i)
    d[(size_t)(n0 + ty + 8 * i) * K + k0 + tx] = (__bf16)t[tx][ty + 8 * i];
}

__global__ void cvt_k(const float* __restrict__ src, __bf16* __restrict__ dst, int n8)
{
  const int i = blockIdx.x * 256 + threadIdx.x;
  if (i >= n8) return;
  const float4 a = *(const float4*)&src[(size_t)i * 8];
  const float4 b = *(const float4*)&src[(size_t)i * 8 + 4];
  bf16x8 o;
  o[0] = (__bf16)a.x; o[1] = (__bf16)a.y; o[2] = (__bf16)a.z; o[3] = (__bf16)a.w;
  o[4] = (__bf16)b.x; o[5] = (__bf16)b.y; o[6] = (__bf16)b.z; o[7] = (__bf16)b.w;
  *(bf16x8*)&dst[(size_t)i * 8] = o;
}

// ---------------------------------------------------------------------
__global__ __launch_bounds__(256) void embed_k(
    const float* __restrict__ pe, const float* __restrict__ cls,
    const float* __restrict__ pos, float* __restrict__ h)
{
  const int i = blockIdx.x * 256 + threadIdx.x;
  const int row = i / 96;
  const int d4 = (i - row * 96) * 4;
  const int b = row / TSEQ;
  const int t = row - b * TSEQ;
  const float4 po = *(const float4*)&pos[(size_t)t * DMODEL + d4];
  float4 r;
  if (t == 0) {
    const float4 cv = *(const float4*)&cls[d4];
    r = make_float4(cv.x + po.x, cv.y + po.y, cv.z + po.z, cv.w + po.w);
  } else {
    const float4 pv = *(const float4*)&pe[((size_t)(b * NPATCHI + t - 1)) * DMODEL + d4];
    r = make_float4(pv.x + po.x, pv.y + po.y, pv.z + po.z, pv.w + po.w);
  }
  *(float4*)&h[(size_t)row * DMODEL + d4] = r;
}

// ---------------------------------------------------------------------
__global__ __launch_bounds__(256) void ln_k(
    const float* __restrict__ in, const float* __restrict__ sc,
    const float* __restrict__ bi, __bf16* __restrict__ out)
{
  const int w = threadIdx.x >> 6, lane = threadIdx.x & 63;
  const int row = blockIdx.x * 4 + w;
  const float* r = in + (size_t)row * DMODEL;
  float v[6], sum = 0.f, ss = 0.f;
#pragma unroll
  for (int j = 0; j < 6; ++j) {
    const float xv = r[lane + 64 * j];
    v[j] = xv; sum += xv; ss += xv * xv;
  }
#pragma unroll
  for (int m = 1; m < 64; m <<= 1) {
    sum += __shfl_xor(sum, m, 64);
    ss  += __shfl_xor(ss,  m, 64);
  }
  const float mean = sum * (1.f / 384.f);
  const float var  = ss * (1.f / 384.f) - mean * mean;
  const float rstd = rsqrtf(var + 1e-5f);
  __bf16* o = out + (size_t)row * DMODEL;
#pragma unroll
  for (int j = 0; j < 6; ++j) {
    const int col = lane + 64 * j;
    o[col] = (__bf16)((v[j] - mean) * rstd * sc[col] + bi[col]);
  }
}

// ---------------------------------------------------------------------
__global__ __launch_bounds__(256) void sumsq_k(
    const __bf16* __restrict__ qkv, float* __restrict__ sq2,
    float* __restrict__ sk2)
{
  const int w = threadIdx.x >> 6, lane = threadIdx.x & 63;
  const int row = blockIdx.x * 4 + w;
  const int h = lane >> 4, lg = lane & 15;
  const __bf16* q = qkv + (size_t)row * 1152 + h * HDIM;
  float s1 = 0.f, s2 = 0.f;
#pragma unroll
  for (int j = 0; j < 6; ++j) {
    const float a = (float)q[lg + 16 * j];
    const float c = (float)q[384 + lg + 16 * j];
    s1 += a * a; s2 += c * c;
  }
#pragma unroll
  for (int m = 1; m < 16; m <<= 1) {
    s1 += __shfl_xor(s1, m, 64);
    s2 += __shfl_xor(s2, m, 64);
  }
  if (lg == 0) {
    const int b = row / TSEQ, t = row - b * TSEQ;
    sq2[((size_t)b * NHEAD + h) * TSEQ + t] = s1;
    sk2[((size_t)b * NHEAD + h) * TSEQ + t] = s2;
  }
}

// ---------------------------------------------------------------------
__global__ __launch_bounds__(256) void head_k(
    const float* __restrict__ h, const float* __restrict__ gs,
    const float* __restrict__ gb, const float* __restrict__ pw,
    const float* __restrict__ pb, const int* __restrict__ tgt,
    float* __restrict__ out)
{
  __shared__ float lg[BATCH][2];
  const int w = threadIdx.x >> 6, lane = threadIdx.x & 63;
  for (int b = w; b < BATCH; b += 4) {
    const float* r = h + (size_t)b * TSEQ * DMODEL;
    float v[6], sum = 0.f, ss = 0.f;
#pragma unroll
    for (int j = 0; j < 6; ++j) {
      const float xv = r[lane + 64 * j];
      v[j] = xv; sum += xv; ss += xv * xv;
    }
#pragma unroll
    for (int m = 1; m < 64; m <<= 1) {
      sum += __shfl_xor(sum, m, 64);
      ss  += __shfl_xor(ss,  m, 64);
    }
    const float mean = sum * (1.f / 384.f);
    const float var  = ss * (1.f / 384.f) - mean * mean;
    const float rstd = rsqrtf(var + 1e-5f);
    float l0 = 0.f, l1 = 0.f;
#pragma unroll
    for (int j = 0; j < 6; ++j) {
      const int col = lane + 64 * j;
      const float hnv = (v[j] - mean) * rstd * gs[col] + gb[col];
      l0 = fmaf(hnv, pw[col * 2 + 0], l0);
      l1 = fmaf(hnv, pw[col * 2 + 1], l1);
    }
#pragma unroll
    for (int m = 1; m < 64; m <<= 1) {
      l0 += __shfl_xor(l0, m, 64);
      l1 += __shfl_xor(l1, m, 64);
    }
    if (lane == 0) { lg[b][0] = l0 + pb[0]; lg[b][1] = l1 + pb[1]; }
  }
  __syncthreads();
  if (threadIdx.x < 32)
    out[threadIdx.x] = lg[threadIdx.x >> 1][threadIdx.x & 1];
  if (threadIdx.x == 0) {
    float acc = 0.f;
    for (int b = 0; b < BATCH; ++b) {
      const float a = lg[b][0], c = lg[b][1];
      const float mx = fmaxf(a, c);
      const float lse = mx + logf(expf(a - mx) + expf(c - mx));
      const float lp = ((tgt[b] == 0) ? a : c) - lse;
      acc += lp;
    }
    out[32] = -acc * (1.f / BATCH);
  }
}

// ---------------------------------------------------------------------
extern "C" void kernel_launch(void* const* d_in, const int* in_sizes, int n_in,
                              void* d_out, int out_size, void* d_ws, size_t ws_size,
                              hipStream_t stream)
{
  const float* x       = (const float*)d_in[0];
  const int*   targets = (const int*)  d_in[1];
  const float* conv_w  = (const float*)d_in[2];
  const float* conv_b  = (const float*)d_in[3];
  const float* cls_tok = (const float*)d_in[4];
  const float* pos_emb = (const float*)d_in[5];
  const float* ln1_s   = (const float*)d_in[6];
  const float* ln1_b   = (const float*)d_in[7];
  const float* ln2_s   = (const float*)d_in[8];
  const float* ln2_b   = (const float*)d_in[9];
  const float* wq      = (const float*)d_in[10];
  const float* wk      = (const float*)d_in[11];
  const float* wv      = (const float*)d_in[12];
  const float* wo      = (const float*)d_in[13];
  const float* bo      = (const float*)d_in[14];
  const float* w1      = (const float*)d_in[15];
  const float* b1      = (const float*)d_in[16];
  const float* w2      = (const float*)d_in[17];
  const float* b2      = (const float*)d_in[18];
  const float* lnf_s   = (const float*)d_in[19];
  const float* lnf_b   = (const float*)d_in[20];
  const float* proj_w  = (const float*)d_in[21];
  const float* proj_b  = (const float*)d_in[22];

  char* p = (char*)d_ws;
  auto alloc = [&](size_t bytes) -> void* {
    void* r = (void*)p; p += (bytes + 255) & ~(size_t)255; return r;
  };
  float*  h     = (float*) alloc((size_t)MROWS * DMODEL * 4);
  __bf16* hn    = (__bf16*)alloc((size_t)MROWS * DMODEL * 2);
  __bf16* qkv   = (__bf16*)alloc((size_t)MROWS * 1152 * 2);
  __bf16* Obuf  = (__bf16*)alloc((size_t)MROWS * DMODEL * 2);
  float*  pe    = (float*) alloc((size_t)MPATCH * DMODEL * 4);    // 25.17 MB
  float*  sq2   = (float*) alloc((size_t)BATCH * NHEAD * TSEQ * 4);
  float*  sk2   = (float*) alloc((size_t)BATCH * NHEAD * TSEQ * 4);
  __bf16* cwb   = (__bf16*)alloc((size_t)DMODEL * KPE * 2);
  __bf16* wqkvT = (__bf16*)alloc((size_t)NBLK * 1152 * DMODEL * 2);
  __bf16* woT   = (__bf16*)alloc((size_t)NBLK * DMODEL * DMODEL * 2);
  __bf16* w1T   = (__bf16*)alloc((size_t)NBLK * FFDIM * DMODEL * 2);
  __bf16* w2T   = (__bf16*)alloc((size_t)NBLK * DMODEL * FFDIM * 2);
  if ((size_t)(p - (char*)d_ws) > ws_size) return;
  __bf16* Ai  = qkv;           // im2col buffer, dead before QKV
  __bf16* ffb = qkv;           // MLP hidden spans qkv+Obuf exactly
  __bf16* Vtg = (__bf16*)pe;   // Vt[64][112][1088] = 15.6 MB <= pe (25.17 MB)

  // ---- weight conversion ----
  cvt_k<<<144, 256, 0, stream>>>(conv_w, cwb, (DMODEL * KPE) / 8);
  {
    dim3 blk(32, 8);
    wt_k<<<dim3(12, 12, 3), blk, 0, stream>>>(wq, (size_t)DMODEL * DMODEL,
        wqkvT + 0,               (size_t)1152 * DMODEL, DMODEL, DMODEL);
    wt_k<<<dim3(12, 12, 3), blk, 0, stream>>>(wk, (size_t)DMODEL * DMODEL,
        wqkvT + 384 * DMODEL,    (size_t)1152 * DMODEL, DMODEL, DMODEL);
    wt_k<<<dim3(12, 12, 3), blk, 0, stream>>>(wv, (size_t)DMODEL * DMODEL,
        wqkvT + 768 * DMODEL,    (size_t)1152 * DMODEL, DMODEL, DMODEL);
    wt_k<<<dim3(12, 12, 3), blk, 0, stream>>>(wo, (size_t)DMODEL * DMODEL,
        woT, (size_t)DMODEL * DMODEL, DMODEL, DMODEL);
    wt_k<<<dim3(12, 48, 3), blk, 0, stream>>>(w1, (size_t)DMODEL * FFDIM,
        w1T, (size_t)FFDIM * DMODEL, DMODEL, FFDIM);
    wt_k<<<dim3(48, 12, 3), blk, 0, stream>>>(w2, (size_t)FFDIM * DMODEL,
        w2T, (size_t)DMODEL * FFDIM, FFDIM, DMODEL);
  }

  // ---- patch embedding ----
  im2col_k<<<6144, 256, 0, stream>>>(x, Ai);
  mgemm_k<9><<<dim3(128, 3), 256, 0, stream>>>(
      Ai, cwb, conv_b, nullptr, pe, nullptr, MPATCH, DMODEL, KPE);
  embed_k<<<6150, 256, 0, stream>>>(pe, cls_tok, pos_emb, h);

  // ---- transformer blocks ----
  for (int i = 0; i < NBLK; ++i) {
    ln_k<<<4100, 256, 0, stream>>>(h, ln1_s + i * DMODEL, ln1_b + i * DMODEL, hn);
    mgemm_k<16><<<dim3(129, 9), 256, 0, stream>>>(
        hn, wqkvT + (size_t)i * 1152 * DMODEL, nullptr, nullptr,
        nullptr, qkv, MROWS, 1152, DMODEL);
    sumsq_k<<<4100, 256, 0, stream>>>(qkv, sq2, sk2);
    vtr_k<<<dim3(34, 4, 64), dim3(32, 8), 0, stream>>>(qkv, Vtg);
    attn_k<<<dim3(17, 64), 256, 0, stream>>>(qkv, Vtg, sq2, sk2, Obuf);
    mgemm_k<13><<<dim3(129, 3), 256, 0, stream>>>(
        Obuf, woT + (size_t)i * DMODEL * DMODEL, bo + i * DMODEL, h,
        h, nullptr, MROWS, DMODEL, DMODEL);
    ln_k<<<4100, 256, 0, stream>>>(h, ln2_s + i * DMODEL, ln2_b + i * DMODEL, hn);
    mgemm_k<19><<<dim3(129, 12), 256, 0, stream>>>(
        hn, w1T + (size_t)i * FFDIM * DMODEL, b1 + i * FFDIM, nullptr,
        nullptr, ffb, MROWS, FFDIM, DMODEL);
    mgemm_k<13><<<dim3(129, 3), 256, 0, stream>>>(
        ffb, w2T + (size_t)i * DMODEL * FFDIM, b2 + i * DMODEL, h,
        h, nullptr, MROWS, DMODEL, FFDIM);
  }

  // ---- head ----
  head_k<<<1, 256, 0, stream>>>(h, lnf_s, lnf_b, proj_w, proj_b, targets,
                                (float*)d_out);
}

// Round 5
// 1143.311 us; speedup vs baseline: 1.3381x; 1.3381x over previous
//
#include <hip/hip_runtime.h>
#include <math.h>

// =====================================================================
// ViT discriminator forward — round 5.
// attn rewritten: LDS-staged (round-3 base) + swapped-QK (S^T via
// mfma(K,Q): softmax state scalar per lane), defer-max, b64-packed P,
// double-buffered K/V (1 barrier/chunk), 32 q/wave (128-row tiles),
// XCD-swizzled block mapping (72 blocks/XCD share 8 heads -> L2-fit).
// mgemm: round-4 global_load_lds version (neutral, kept).
// =====================================================================

#define BATCH   16
#define TSEQ    1025
#define DMODEL  384
#define NHEAD   4
#define HDIM    96
#define NBLK    3
#define FFDIM   1536
#define IMGSZ   512
#define NPATCHI 1024
#define MROWS   (BATCH*TSEQ)      // 16400
#define MPATCH  (BATCH*NPATCHI)   // 16384
#define KPE     768
#define VTS     1088              // padded t-stride of Vt (17*64)
#define SKS     1088              // padded t-stride of sq2/sk2
#define ATT_SCALE 0.10206207261596577f  // 1/sqrt(96)

typedef __attribute__((ext_vector_type(8))) __bf16 bf16x8;
typedef __attribute__((ext_vector_type(4))) __bf16 bf16x4;
typedef __attribute__((ext_vector_type(4))) float  f32x4;
typedef unsigned int u32;

__device__ __forceinline__ f32x4 fzero4() {
  f32x4 v; v[0] = 0.f; v[1] = 0.f; v[2] = 0.f; v[3] = 0.f; return v;
}
__device__ __forceinline__ bf16x8 bzero8() {
  bf16x8 v;
#pragma unroll
  for (int j = 0; j < 8; ++j) v[j] = (__bf16)0.f;
  return v;
}

// async global->LDS, 16B per lane, LDS dest = wave-uniform base + lane*16
__device__ __forceinline__ void gl_lds16(const __bf16* g, __bf16* l) {
  __builtin_amdgcn_global_load_lds(
      (const __attribute__((address_space(1))) u32*)g,
      (__attribute__((address_space(3))) u32*)l, 16, 0, 0);
}

// ---------------------------------------------------------------------
// bf16 MFMA GEMM: C[M,N] = A[M,K] @ Bt[N,K]^T, K%32==0, N%128==0.
// global_load_lds staging, linear LDS, 1 barrier / K-step.
// EPI bits: 1=+bias, 2=relu, 4=+res(fp32), 8=write Cf(fp32), 16=write Cb(bf16)
// ---------------------------------------------------------------------
template<int EPI>
__global__ __launch_bounds__(256, 4) void mgemm_k(
    const __bf16* __restrict__ A, const __bf16* __restrict__ Bt,
    const float* __restrict__ bias, const float* __restrict__ res,
    float* __restrict__ Cf, __bf16* __restrict__ Cb, int M, int N, int K)
{
  __shared__ __bf16 Al[2][128][32];
  __shared__ __bf16 Bl[2][128][32];
  const int tid = threadIdx.x;
  const int lane = tid & 63;
  const int w = tid >> 6;
  const int wr = w >> 1, wc = w & 1;
  const int l15 = lane & 15, g = lane >> 4;
  const int row0 = blockIdx.x * 128, col0 = blockIdx.y * 128;
  const int sr = w * 32 + (lane >> 2);
  const int sc = (lane & 3) * 8;
  const __bf16* Ab = A  + (size_t)(row0 + sr) * K + sc;
  const __bf16* Bb = Bt + (size_t)(col0 + sr) * K + sc;

  f32x4 acc[4][4];
#pragma unroll
  for (int i = 0; i < 4; ++i)
#pragma unroll
    for (int j = 0; j < 4; ++j) acc[i][j] = fzero4();

  const int nk = K >> 5;
  auto stage = [&](int buf, int kt) {
#pragma unroll
    for (int j = 0; j < 2; ++j) {
      gl_lds16(Ab + (size_t)(j * 16) * K + kt * 32, &Al[buf][w * 32 + j * 16][0]);
      gl_lds16(Bb + (size_t)(j * 16) * K + kt * 32, &Bl[buf][w * 32 + j * 16][0]);
    }
  };

  stage(0, 0);
  __syncthreads();
  int cur = 0;
  for (int kt = 0; kt < nk; ++kt) {
    if (kt + 1 < nk) stage(cur ^ 1, kt + 1);
    bf16x8 af[4], bfr[4];
#pragma unroll
    for (int mi = 0; mi < 4; ++mi)
      af[mi] = *(const bf16x8*)&Al[cur][wr * 64 + mi * 16 + l15][g * 8];
#pragma unroll
    for (int ni = 0; ni < 4; ++ni)
      bfr[ni] = *(const bf16x8*)&Bl[cur][wc * 64 + ni * 16 + l15][g * 8];
    __builtin_amdgcn_s_setprio(1);
#pragma unroll
    for (int mi = 0; mi < 4; ++mi)
#pragma unroll
      for (int ni = 0; ni < 4; ++ni)
        acc[mi][ni] = __builtin_amdgcn_mfma_f32_16x16x32_bf16(
            af[mi], bfr[ni], acc[mi][ni], 0, 0, 0);
    __builtin_amdgcn_s_setprio(0);
    __syncthreads();
    cur ^= 1;
  }
#pragma unroll
  for (int ni = 0; ni < 4; ++ni) {
    const int gc = col0 + wc * 64 + ni * 16 + l15;
    const float bv = (EPI & 1) ? bias[gc] : 0.f;
#pragma unroll
    for (int mi = 0; mi < 4; ++mi) {
#pragma unroll
      for (int r = 0; r < 4; ++r) {
        const int gr = row0 + wr * 64 + mi * 16 + g * 4 + r;
        if (gr >= M) continue;
        float v = acc[mi][ni][r] + bv;
        if (EPI & 2) v = fmaxf(v, 0.f);
        if (EPI & 4) v += res[(size_t)gr * N + gc];
        if (EPI & 8)  Cf[(size_t)gr * N + gc] = v;
        if (EPI & 16) Cb[(size_t)gr * N + gc] = (__bf16)v;
      }
    }
  }
}

// ---------------------------------------------------------------------
// V transpose: Vt[bh][96][VTS] <- qkv[.,768+h*96+.]; zero-fill t>=TSEQ
// ---------------------------------------------------------------------
__global__ void vtr_k(const __bf16* __restrict__ qkv, __bf16* __restrict__ Vt)
{
  __shared__ __bf16 t[32][33];
  const int bh = blockIdx.z;
  const int bb = bh >> 2, hh = bh & 3;
  const int t0 = blockIdx.x * 32;
  const int d0 = blockIdx.y * 32;
  const int tx = threadIdx.x, ty = threadIdx.y;  // 32 x 8
#pragma unroll
  for (int i = 0; i < 4; ++i) {
    const int tt = t0 + ty + 8 * i;
    t[ty + 8 * i][tx] = (tt < TSEQ)
        ? qkv[(size_t)(bb * TSEQ + tt) * 1152 + 768 + hh * 96 + d0 + tx]
        : (__bf16)0.f;
  }
  __syncthreads();
#pragma unroll
  for (int i = 0; i < 4; ++i)
    Vt[((size_t)bh * 96 + d0 + ty + 8 * i) * VTS + t0 + tx] = t[tx][ty + 8 * i];
}

// ---------------------------------------------------------------------
// Swapped-QK MFMA distance attention, round 5.
// Grid 576 = 9 q-tiles x 64 bh, XCD-swizzled. 4 waves x 32 q-rows.
// S^T = mfma(K, Q): lane (g,l15) holds scores for q=m*16+l15,
// keys ks*16+g*4+r -> softmax state (mrun,lrun) scalar per lane per m.
// ---------------------------------------------------------------------
__global__ __launch_bounds__(256, 2) void attn_k(
    const __bf16* __restrict__ qkv, const __bf16* __restrict__ Vtg,
    const float* __restrict__ sq2, const float* __restrict__ sk2,
    __bf16* __restrict__ O)
{
  __shared__ __bf16 Kl[2][64][104];   // 208B rows (16B-mult, ~2-way banks)
  __shared__ __bf16 Vl[2][96][72];    // 144B rows
  __shared__ __bf16 Pl[4][32][72];    // per-wave P rows (q-major)
  // XCD-aware decode: xcd = bid&7 gets contiguous bh range (8 heads)
  const int bid = blockIdx.x;
  const int xcd = bid & 7, jj = bid >> 3;       // jj in [0,72)
  const int j9 = jj / 9;
  const int bh = xcd * 8 + j9;
  const int qt = jj - j9 * 9;
  const int bb = bh >> 2, hh = bh & 3;
  const int tid = threadIdx.x;
  const int w = tid >> 6, lane = tid & 63;
  const int l15 = lane & 15, g = lane >> 4;
  const int q0 = qt * 128 + w * 32;
  const float* sq2h = sq2 + (size_t)bh * SKS;
  const float* sk2h = sk2 + (size_t)bh * SKS;
  const __bf16* vbase = Vtg + (size_t)bh * 96 * VTS;

  // ---- Q fragments (B-operand) + |q|^2 (scalar per lane, q=m*16+l15) ----
  bf16x8 qf[2][3];
  float sqv[2];
#pragma unroll
  for (int m = 0; m < 2; ++m) {
    int qr = q0 + m * 16 + l15; if (qr > TSEQ - 1) qr = TSEQ - 1;
    const __bf16* qp = qkv + (size_t)(bb * TSEQ + qr) * 1152 + hh * 96 + g * 8;
#pragma unroll
    for (int kf = 0; kf < 3; ++kf) qf[m][kf] = *(const bf16x8*)(qp + kf * 32);
    sqv[m] = sq2h[qr];
  }

  float mrun[2] = {-INFINITY, -INFINITY};
  float lrun[2] = {0.f, 0.f};
  f32x4 accO[2][6];
#pragma unroll
  for (int m = 0; m < 2; ++m)
#pragma unroll
    for (int n = 0; n < 6; ++n) accO[m][n] = fzero4();

  bf16x8 kr[3], vr[3];
  auto load_chunk = [&](int c) {
    const int kbase = c * 64;
#pragma unroll
    for (int i = 0; i < 3; ++i) {
      const int idx = tid + i * 256;
      const int row = idx / 12, cc = idx - row * 12;   // K: 64 rows x 12 oct
      const int kg = kbase + row;
      kr[i] = (kg < TSEQ)
          ? *(const bf16x8*)(qkv + (size_t)(bb * TSEQ + kg) * 1152 + 384
                             + hh * 96 + cc * 8)
          : bzero8();
      const int d = idx >> 3, o8 = (idx & 7) * 8;      // V: 96 rows x 8 oct
      vr[i] = *(const bf16x8*)(vbase + (size_t)d * VTS + kbase + o8);
    }
  };

  load_chunk(0);
  int cur = 0;
  for (int c = 0; c < 17; ++c) {
    const int kbase = c * 64;
    // ---- publish chunk c to LDS buf[cur] ----
#pragma unroll
    for (int i = 0; i < 3; ++i) {
      const int idx = tid + i * 256;
      const int row = idx / 12, cc = idx - row * 12;
      *(bf16x8*)&Kl[cur][row][cc * 8] = kr[i];
      const int d = idx >> 3, o8 = (idx & 7) * 8;
      *(bf16x8*)&Vl[cur][d][o8] = vr[i];
    }
    __syncthreads();
    if (c < 16) load_chunk(c + 1);     // global latency hides under compute

    // ---- S^T = K Q^T ----
    f32x4 sfT[2][4];
#pragma unroll
    for (int m = 0; m < 2; ++m)
#pragma unroll
      for (int ks = 0; ks < 4; ++ks) sfT[m][ks] = fzero4();
    __builtin_amdgcn_s_setprio(1);
#pragma unroll
    for (int ks = 0; ks < 4; ++ks) {
      bf16x8 kb0 = *(const bf16x8*)&Kl[cur][ks * 16 + l15][g * 8];
      bf16x8 kb1 = *(const bf16x8*)&Kl[cur][ks * 16 + l15][32 + g * 8];
      bf16x8 kb2 = *(const bf16x8*)&Kl[cur][ks * 16 + l15][64 + g * 8];
#pragma unroll
      for (int m = 0; m < 2; ++m) {
        sfT[m][ks] = __builtin_amdgcn_mfma_f32_16x16x32_bf16(kb0, qf[m][0], sfT[m][ks], 0, 0, 0);
        sfT[m][ks] = __builtin_amdgcn_mfma_f32_16x16x32_bf16(kb1, qf[m][1], sfT[m][ks], 0, 0, 0);
        sfT[m][ks] = __builtin_amdgcn_mfma_f32_16x16x32_bf16(kb2, qf[m][2], sfT[m][ks], 0, 0, 0);
      }
    }
    __builtin_amdgcn_s_setprio(0);

    // ---- distance scores (key = kbase + ks*16 + g*4 + r) ----
    float cm[2] = {-INFINITY, -INFINITY};
#pragma unroll
    for (int ks = 0; ks < 4; ++ks) {
      const int sb = kbase + ks * 16 + g * 4;
      const float4 skv = *(const float4*)&sk2h[sb];   // SKS-padded: in-bounds
      const float sk4[4] = {skv.x, skv.y, skv.z, skv.w};
#pragma unroll
      for (int m = 0; m < 2; ++m)
#pragma unroll
        for (int r = 0; r < 4; ++r) {
          const float d2 = sqv[m] + sk4[r] - 2.f * sfT[m][ks][r];
          const float s = (sb + r < TSEQ)
              ? sqrtf(fmaxf(d2, 0.f)) * ATT_SCALE : -INFINITY;
          sfT[m][ks][r] = s;
          cm[m] = fmaxf(cm[m], s);
        }
    }

    // ---- defer-max: rescale only when chunk max grows past THR=8 ----
    const int ok = (cm[0] <= mrun[0] + 8.f) && (cm[1] <= mrun[1] + 8.f);
    if (!__all(ok)) {
#pragma unroll
      for (int m = 0; m < 2; ++m) {
        float v = cm[m];
        v = fmaxf(v, __shfl_xor(v, 16, 64));
        v = fmaxf(v, __shfl_xor(v, 32, 64));
        const float mn = fmaxf(mrun[m], v);
        const float f = __expf(mrun[m] - mn);
        mrun[m] = mn;
        lrun[m] *= f;
#pragma unroll
        for (int r = 0; r < 4; ++r) {
          const float fb = __shfl(f, g * 4 + r, 64);  // f for q-local g*4+r
#pragma unroll
          for (int n = 0; n < 6; ++n) accO[m][n][r] *= fb;
        }
      }
    }

    // ---- P = exp(s - m): packed b64 writes to wave-private Pl ----
#pragma unroll
    for (int m = 0; m < 2; ++m) {
      float psum = 0.f;
#pragma unroll
      for (int ks = 0; ks < 4; ++ks) {
        bf16x4 pw;
#pragma unroll
        for (int r = 0; r < 4; ++r) {
          const float p = __expf(sfT[m][ks][r] - mrun[m]);
          psum += p;
          pw[r] = (__bf16)p;
        }
        *(bf16x4*)&Pl[w][m * 16 + l15][ks * 16 + g * 4] = pw;
      }
      psum += __shfl_xor(psum, 16, 64);
      psum += __shfl_xor(psum, 32, 64);
      lrun[m] += psum;
    }

    // ---- O += P V ----
    __builtin_amdgcn_s_setprio(1);
#pragma unroll
    for (int ks2 = 0; ks2 < 2; ++ks2) {
      bf16x8 pa[2];
#pragma unroll
      for (int m = 0; m < 2; ++m)
        pa[m] = *(const bf16x8*)&Pl[w][m * 16 + l15][ks2 * 32 + g * 8];
#pragma unroll
      for (int n = 0; n < 6; ++n) {
        bf16x8 vb = *(const bf16x8*)&Vl[cur][n * 16 + l15][ks2 * 32 + g * 8];
#pragma unroll
        for (int m = 0; m < 2; ++m)
          accO[m][n] = __builtin_amdgcn_mfma_f32_16x16x32_bf16(pa[m], vb, accO[m][n], 0, 0, 0);
      }
    }
    __builtin_amdgcn_s_setprio(0);
    cur ^= 1;
  }

  // ---- normalize + store (D rows = q-local m*16+g*4+r, cols = n*16+l15) ----
#pragma unroll
  for (int m = 0; m < 2; ++m)
#pragma unroll
    for (int r = 0; r < 4; ++r) {
      const int qr = q0 + m * 16 + g * 4 + r;
      if (qr >= TSEQ) continue;
      const float lv = __shfl(lrun[m], g * 4 + r, 64);
      const float inv = 1.f / lv;
#pragma unroll
      for (int n = 0; n < 6; ++n)
        O[(size_t)(bb * TSEQ + qr) * 384 + hh * 96 + n * 16 + l15] =
            (__bf16)(accO[m][n][r] * inv);
    }
}

// ---------------------------------------------------------------------
// im2col + fp32->bf16: Ai[16384][768]
// ---------------------------------------------------------------------
__global__ __launch_bounds__(256) void im2col_k(
    const float* __restrict__ x, __bf16* __restrict__ Ai)
{
  const int i = blockIdx.x * 256 + threadIdx.x;
  const int row = i / 96;
  const int k = (i - row * 96) * 8;
  const int b = row >> 10;
  const int pidx = row & 1023;
  const int py = pidx >> 5, px = pidx & 31;
  const int cc = k >> 8;
  const int rem = k & 255;
  const int p = rem >> 4, q = rem & 15;
  const float* src = x + ((size_t)((b * 3 + cc) * IMGSZ + py * 16 + p)) * IMGSZ
                       + px * 16 + q;
  const float4 a = *(const float4*)src;
  const float4 c4 = *(const float4*)(src + 4);
  bf16x8 o;
  o[0] = (__bf16)a.x;  o[1] = (__bf16)a.y;  o[2] = (__bf16)a.z;  o[3] = (__bf16)a.w;
  o[4] = (__bf16)c4.x; o[5] = (__bf16)c4.y; o[6] = (__bf16)c4.z; o[7] = (__bf16)c4.w;
  *(bf16x8*)&Ai[(size_t)i * 8] = o;
}

// ---------------------------------------------------------------------
__global__ void wt_k(const float* __restrict__ src, size_t srcZ,
                     __bf16* __restrict__ dst, size_t dstZ, int K, int N)
{
  __shared__ float t[32][33];
  const float* s = src + blockIdx.z * srcZ;
  __bf16* d = dst + blockIdx.z * dstZ;
  const int k0 = blockIdx.x * 32, n0 = blockIdx.y * 32;
  const int tx = threadIdx.x, ty = threadIdx.y;
#pragma unroll
  for (int i = 0; i < 4; ++i)
    t[ty + 8 * i][tx] = s[(size_t)(k0 + ty + 8 * i) * N + n0 + tx];
  __syncthreads();
#pragma unroll
  for (int i = 0; i < 4; ++i)
    d[(size_t)(n0 + ty + 8 * i) * K + k0 + tx] = (__bf16)t[tx][ty + 8 * i];
}

__global__ void cvt_k(const float* __restrict__ src, __bf16* __restrict__ dst, int n8)
{
  const int i = blockIdx.x * 256 + threadIdx.x;
  if (i >= n8) return;
  const float4 a = *(const float4*)&src[(size_t)i * 8];
  const float4 b = *(const float4*)&src[(size_t)i * 8 + 4];
  bf16x8 o;
  o[0] = (__bf16)a.x; o[1] = (__bf16)a.y; o[2] = (__bf16)a.z; o[3] = (__bf16)a.w;
  o[4] = (__bf16)b.x; o[5] = (__bf16)b.y; o[6] = (__bf16)b.z; o[7] = (__bf16)b.w;
  *(bf16x8*)&dst[(size_t)i * 8] = o;
}

// ---------------------------------------------------------------------
__global__ __launch_bounds__(256) void embed_k(
    const float* __restrict__ pe, const float* __restrict__ cls,
    const float* __restrict__ pos, float* __restrict__ h)
{
  const int i = blockIdx.x * 256 + threadIdx.x;
  const int row = i / 96;
  const int d4 = (i - row * 96) * 4;
  const int b = row / TSEQ;
  const int t = row - b * TSEQ;
  const float4 po = *(const float4*)&pos[(size_t)t * DMODEL + d4];
  float4 r;
  if (t == 0) {
    const float4 cv = *(const float4*)&cls[d4];
    r = make_float4(cv.x + po.x, cv.y + po.y, cv.z + po.z, cv.w + po.w);
  } else {
    const float4 pv = *(const float4*)&pe[((size_t)(b * NPATCHI + t - 1)) * DMODEL + d4];
    r = make_float4(pv.x + po.x, pv.y + po.y, pv.z + po.z, pv.w + po.w);
  }
  *(float4*)&h[(size_t)row * DMODEL + d4] = r;
}

// ---------------------------------------------------------------------
__global__ __launch_bounds__(256) void ln_k(
    const float* __restrict__ in, const float* __restrict__ sc,
    const float* __restrict__ bi, __bf16* __restrict__ out)
{
  const int w = threadIdx.x >> 6, lane = threadIdx.x & 63;
  const int row = blockIdx.x * 4 + w;
  const float* r = in + (size_t)row * DMODEL;
  float v[6], sum = 0.f, ss = 0.f;
#pragma unroll
  for (int j = 0; j < 6; ++j) {
    const float xv = r[lane + 64 * j];
    v[j] = xv; sum += xv; ss += xv * xv;
  }
#pragma unroll
  for (int m = 1; m < 64; m <<= 1) {
    sum += __shfl_xor(sum, m, 64);
    ss  += __shfl_xor(ss,  m, 64);
  }
  const float mean = sum * (1.f / 384.f);
  const float var  = ss * (1.f / 384.f) - mean * mean;
  const float rstd = rsqrtf(var + 1e-5f);
  __bf16* o = out + (size_t)row * DMODEL;
#pragma unroll
  for (int j = 0; j < 6; ++j) {
    const int col = lane + 64 * j;
    o[col] = (__bf16)((v[j] - mean) * rstd * sc[col] + bi[col]);
  }
}

// ---------------------------------------------------------------------
__global__ __launch_bounds__(256) void sumsq_k(
    const __bf16* __restrict__ qkv, float* __restrict__ sq2,
    float* __restrict__ sk2)
{
  const int w = threadIdx.x >> 6, lane = threadIdx.x & 63;
  const int row = blockIdx.x * 4 + w;
  const int h = lane >> 4, lg = lane & 15;
  const __bf16* q = qkv + (size_t)row * 1152 + h * HDIM;
  float s1 = 0.f, s2 = 0.f;
#pragma unroll
  for (int j = 0; j < 6; ++j) {
    const float a = (float)q[lg + 16 * j];
    const float c = (float)q[384 + lg + 16 * j];
    s1 += a * a; s2 += c * c;
  }
#pragma unroll
  for (int m = 1; m < 16; m <<= 1) {
    s1 += __shfl_xor(s1, m, 64);
    s2 += __shfl_xor(s2, m, 64);
  }
  if (lg == 0) {
    const int b = row / TSEQ, t = row - b * TSEQ;
    sq2[((size_t)b * NHEAD + h) * SKS + t] = s1;
    sk2[((size_t)b * NHEAD + h) * SKS + t] = s2;
  }
}

// ---------------------------------------------------------------------
__global__ __launch_bounds__(256) void head_k(
    const float* __restrict__ h, const float* __restrict__ gs,
    const float* __restrict__ gb, const float* __restrict__ pw,
    const float* __restrict__ pb, const int* __restrict__ tgt,
    float* __restrict__ out)
{
  __shared__ float lg[BATCH][2];
  const int w = threadIdx.x >> 6, lane = threadIdx.x & 63;
  for (int b = w; b < BATCH; b += 4) {
    const float* r = h + (size_t)b * TSEQ * DMODEL;
    float v[6], sum = 0.f, ss = 0.f;
#pragma unroll
    for (int j = 0; j < 6; ++j) {
      const float xv = r[lane + 64 * j];
      v[j] = xv; sum += xv; ss += xv * xv;
    }
#pragma unroll
    for (int m = 1; m < 64; m <<= 1) {
      sum += __shfl_xor(sum, m, 64);
      ss  += __shfl_xor(ss,  m, 64);
    }
    const float mean = sum * (1.f / 384.f);
    const float var  = ss * (1.f / 384.f) - mean * mean;
    const float rstd = rsqrtf(var + 1e-5f);
    float l0 = 0.f, l1 = 0.f;
#pragma unroll
    for (int j = 0; j < 6; ++j) {
      const int col = lane + 64 * j;
      const float hnv = (v[j] - mean) * rstd * gs[col] + gb[col];
      l0 = fmaf(hnv, pw[col * 2 + 0], l0);
      l1 = fmaf(hnv, pw[col * 2 + 1], l1);
    }
#pragma unroll
    for (int m = 1; m < 64; m <<= 1) {
      l0 += __shfl_xor(l0, m, 64);
      l1 += __shfl_xor(l1, m, 64);
    }
    if (lane == 0) { lg[b][0] = l0 + pb[0]; lg[b][1] = l1 + pb[1]; }
  }
  __syncthreads();
  if (threadIdx.x < 32)
    out[threadIdx.x] = lg[threadIdx.x >> 1][threadIdx.x & 1];
  if (threadIdx.x == 0) {
    float acc = 0.f;
    for (int b = 0; b < BATCH; ++b) {
      const float a = lg[b][0], c = lg[b][1];
      const float mx = fmaxf(a, c);
      const float lse = mx + logf(expf(a - mx) + expf(c - mx));
      const float lp = ((tgt[b] == 0) ? a : c) - lse;
      acc += lp;
    }
    out[32] = -acc * (1.f / BATCH);
  }
}

// ---------------------------------------------------------------------
extern "C" void kernel_launch(void* const* d_in, const int* in_sizes, int n_in,
                              void* d_out, int out_size, void* d_ws, size_t ws_size,
                              hipStream_t stream)
{
  const float* x       = (const float*)d_in[0];
  const int*   targets = (const int*)  d_in[1];
  const float* conv_w  = (const float*)d_in[2];
  const float* conv_b  = (const float*)d_in[3];
  const float* cls_tok = (const float*)d_in[4];
  const float* pos_emb = (const float*)d_in[5];
  const float* ln1_s   = (const float*)d_in[6];
  const float* ln1_b   = (const float*)d_in[7];
  const float* ln2_s   = (const float*)d_in[8];
  const float* ln2_b   = (const float*)d_in[9];
  const float* wq      = (const float*)d_in[10];
  const float* wk      = (const float*)d_in[11];
  const float* wv      = (const float*)d_in[12];
  const float* wo      = (const float*)d_in[13];
  const float* bo      = (const float*)d_in[14];
  const float* w1      = (const float*)d_in[15];
  const float* b1      = (const float*)d_in[16];
  const float* w2      = (const float*)d_in[17];
  const float* b2      = (const float*)d_in[18];
  const float* lnf_s   = (const float*)d_in[19];
  const float* lnf_b   = (const float*)d_in[20];
  const float* proj_w  = (const float*)d_in[21];
  const float* proj_b  = (const float*)d_in[22];

  char* p = (char*)d_ws;
  auto alloc = [&](size_t bytes) -> void* {
    void* r = (void*)p; p += (bytes + 255) & ~(size_t)255; return r;
  };
  float*  h     = (float*) alloc((size_t)MROWS * DMODEL * 4);
  __bf16* hn    = (__bf16*)alloc((size_t)MROWS * DMODEL * 2);
  __bf16* qkv   = (__bf16*)alloc((size_t)MROWS * 1152 * 2);
  __bf16* Obuf  = (__bf16*)alloc((size_t)MROWS * DMODEL * 2);
  float*  pe    = (float*) alloc((size_t)MPATCH * DMODEL * 4);    // 25.17 MB
  float*  sq2   = (float*) alloc((size_t)BATCH * NHEAD * SKS * 4);
  float*  sk2   = (float*) alloc((size_t)BATCH * NHEAD * SKS * 4);
  __bf16* cwb   = (__bf16*)alloc((size_t)DMODEL * KPE * 2);
  __bf16* wqkvT = (__bf16*)alloc((size_t)NBLK * 1152 * DMODEL * 2);
  __bf16* woT   = (__bf16*)alloc((size_t)NBLK * DMODEL * DMODEL * 2);
  __bf16* w1T   = (__bf16*)alloc((size_t)NBLK * FFDIM * DMODEL * 2);
  __bf16* w2T   = (__bf16*)alloc((size_t)NBLK * DMODEL * FFDIM * 2);
  if ((size_t)(p - (char*)d_ws) > ws_size) return;
  __bf16* Ai  = qkv;           // im2col buffer, dead before QKV
  __bf16* ffb = qkv;           // MLP hidden spans qkv+Obuf exactly
  __bf16* Vtg = (__bf16*)pe;   // Vt[64][96][1088] = 13.4 MB <= pe (25.17 MB)

  // ---- weight conversion ----
  cvt_k<<<144, 256, 0, stream>>>(conv_w, cwb, (DMODEL * KPE) / 8);
  {
    dim3 blk(32, 8);
    wt_k<<<dim3(12, 12, 3), blk, 0, stream>>>(wq, (size_t)DMODEL * DMODEL,
        wqkvT + 0,               (size_t)1152 * DMODEL, DMODEL, DMODEL);
    wt_k<<<dim3(12, 12, 3), blk, 0, stream>>>(wk, (size_t)DMODEL * DMODEL,
        wqkvT + 384 * DMODEL,    (size_t)1152 * DMODEL, DMODEL, DMODEL);
    wt_k<<<dim3(12, 12, 3), blk, 0, stream>>>(wv, (size_t)DMODEL * DMODEL,
        wqkvT + 768 * DMODEL,    (size_t)1152 * DMODEL, DMODEL, DMODEL);
    wt_k<<<dim3(12, 12, 3), blk, 0, stream>>>(wo, (size_t)DMODEL * DMODEL,
        woT, (size_t)DMODEL * DMODEL, DMODEL, DMODEL);
    wt_k<<<dim3(12, 48, 3), blk, 0, stream>>>(w1, (size_t)DMODEL * FFDIM,
        w1T, (size_t)FFDIM * DMODEL, DMODEL, FFDIM);
    wt_k<<<dim3(48, 12, 3), blk, 0, stream>>>(w2, (size_t)FFDIM * DMODEL,
        w2T, (size_t)DMODEL * FFDIM, FFDIM, DMODEL);
  }

  // ---- patch embedding ----
  im2col_k<<<6144, 256, 0, stream>>>(x, Ai);
  mgemm_k<9><<<dim3(128, 3), 256, 0, stream>>>(
      Ai, cwb, conv_b, nullptr, pe, nullptr, MPATCH, DMODEL, KPE);
  embed_k<<<6150, 256, 0, stream>>>(pe, cls_tok, pos_emb, h);

  // ---- transformer blocks ----
  for (int i = 0; i < NBLK; ++i) {
    ln_k<<<4100, 256, 0, stream>>>(h, ln1_s + i * DMODEL, ln1_b + i * DMODEL, hn);
    mgemm_k<16><<<dim3(129, 9), 256, 0, stream>>>(
        hn, wqkvT + (size_t)i * 1152 * DMODEL, nullptr, nullptr,
        nullptr, qkv, MROWS, 1152, DMODEL);
    sumsq_k<<<4100, 256, 0, stream>>>(qkv, sq2, sk2);
    vtr_k<<<dim3(34, 3, 64), dim3(32, 8), 0, stream>>>(qkv, Vtg);
    attn_k<<<576, 256, 0, stream>>>(qkv, Vtg, sq2, sk2, Obuf);
    mgemm_k<13><<<dim3(129, 3), 256, 0, stream>>>(
        Obuf, woT + (size_t)i * DMODEL * DMODEL, bo + i * DMODEL, h,
        h, nullptr, MROWS, DMODEL, DMODEL);
    ln_k<<<4100, 256, 0, stream>>>(h, ln2_s + i * DMODEL, ln2_b + i * DMODEL, hn);
    mgemm_k<19><<<dim3(129, 12), 256, 0, stream>>>(
        hn, w1T + (size_t)i * FFDIM * DMODEL, b1 + i * FFDIM, nullptr,
        nullptr, ffb, MROWS, FFDIM, DMODEL);
    mgemm_k<13><<<dim3(129, 3), 256, 0, stream>>>(
        ffb, w2T + (size_t)i * DMODEL * FFDIM, b2 + i * DMODEL, h,
        h, nullptr, MROWS, DMODEL, FFDIM);
  }

  // ---- head ----
  head_k<<<1, 256, 0, stream>>>(h, lnf_s, lnf_b, proj_w, proj_b, targets,
                                (float*)d_out);
}